// Round 2
// 112.696 us; speedup vs baseline: 1.0012x; 1.0012x over previous
//
#include <hip/hip_runtime.h>

// Problem constants (match reference)
#define N_ITEMS   64
#define CAPACITY  102.0f
#define N_PGD     120
#define ETA       0.1f

typedef float v2f __attribute__((ext_vector_type(2)));

// ---- DPP helpers: butterfly reductions over 4-lane quads ------------------
//   0xB1 = quad_perm [1,0,3,2] -> lane ^ 1
//   0x4E = quad_perm [2,3,0,1] -> lane ^ 2
// Both are quad-local, so a 4-lane problem-group never leaks into neighbors.
// All 4 lanes end bitwise-identical after the butterfly, so per-group
// decisions (bracket updates, lam) are uniform within the group.
template <int CTRL>
__device__ __forceinline__ float dpp_movf(float x) {
  return __builtin_bit_cast(
      float, __builtin_amdgcn_update_dpp(0, __builtin_bit_cast(int, x), CTRL,
                                         0xF, 0xF, true));
}

__device__ __forceinline__ float grp4_sum(float x) {
  x += dpp_movf<0xB1>(x);
  x += dpp_movf<0x4E>(x);
  return x;
}

__device__ __forceinline__ float grp4_max(float x) {
  x = fmaxf(x, dpp_movf<0xB1>(x));
  x = fmaxf(x, dpp_movf<0x4E>(x));
  return x;
}

__device__ __forceinline__ float clip01(float z) {
  return __builtin_amdgcn_fmed3f(z, 0.0f, 1.0f);  // single v_med3_f32
}

// False-position estimate from the bracket. Invariant: flo > 0 >= fhi
// (Illinois halving scales f-values by 0.5, preserving signs), so
// fhi - flo < 0 strictly -> no divide-by-zero/NaN; the med3 clamp at the
// call site absorbs any rounding excursion outside [lo, hi].
// Single rcp per pick: rcp is a quarter-rate trans op (R12's dual
// speculation added 3 rcps/iter and raised busy time; R14's paired probes
// degraded lam accuracy and refetched more code -- both reverted).
__device__ __forceinline__ float false_pos(float lo, float flo, float hi,
                                           float fhi) {
  const float t = fhi * __builtin_amdgcn_rcpf(fhi - flo);
  return fmaf(-t, hi - lo, hi);  // hi - fhi*(hi-lo)/(fhi-flo)
}

// 4 lanes per row, 16 items per lane. 16384 rows -> 65536 threads
// (1024 waves = 1 wave/SIMD). Measured optimum (R13) across the explored
// config space: 8-lane/2-waves and dual-row layouts cost more instructions
// than their utilization recovery (R7/R11); speculation/probe-pairing on the
// root-finder chain is net-neutral or worse (R12/R14); root extrapolation
// across PGD iterations breaks limit-cycle rows and wastes eval1 at the
// bracket clamp (R15 -- FAILED accuracy, reverted: warm probe must be the
// previous pick itself).
__global__ __launch_bounds__(256, 1) void pgd_knapsack(
    const float* __restrict__ costs, const float* __restrict__ weights,
    float* __restrict__ out) {
  const int tid  = blockIdx.x * 256 + threadIdx.x;
  const int sub  = tid & 3;                 // lane within row-group
  const int base = (tid >> 2) * N_ITEMS + sub * 16;

  v2f w[8], ec[8], x[8], y[8];

  float B;     // bracket half-width: g(-B) = sum(w), g(+B) = 0 by construction
  float flo0;  // f(-B) = sum(w) - CAPACITY, exact, no eval needed
  {
    float cab = 0.0f;
#pragma unroll
    for (int u = 0; u < 4; ++u) {
      const float4 cq = *reinterpret_cast<const float4*>(costs + base + 4 * u);
      const float4 wq =
          *reinterpret_cast<const float4*>(weights + sub * 16 + 4 * u);
      w[2 * u]      = (v2f){wq.x, wq.y};
      w[2 * u + 1]  = (v2f){wq.z, wq.w};
      ec[2 * u]     = (v2f){ETA * cq.x, ETA * cq.y};
      ec[2 * u + 1] = (v2f){ETA * cq.z, ETA * cq.w};
      y[2 * u]      = (v2f){clip01(cq.x), clip01(cq.y)};
      y[2 * u + 1]  = (v2f){clip01(cq.z), clip01(cq.w)};
      cab = fmaxf(cab, fmaxf(fmaxf(fabsf(cq.x), fabsf(cq.y)),
                             fmaxf(fabsf(cq.z), fabsf(cq.w))));
    }
    cab = grp4_max(cab);
    // Every PGD iterate satisfies y_j in [-0.1 - eta*cab, 1 + eta*cab]
    // (since (1 - eta/||x||) * x_j in [-eta, 1]); with w_j >= 1 this makes
    // +-B a valid bracket: all coords clipped to 1 at -B, to 0 at +B.
    B = fmaf(ETA, cab, 1.1f) + 1e-3f;
    v2f sw = (w[0] + w[1]) + (w[2] + w[3]);
    sw = sw + ((w[4] + w[5]) + (w[6] + w[7]));
    flo0 = grp4_sum(sw.x + sw.y) - CAPACITY;  // = 340 - 102, exact
  }
  const float fhi0 = -CAPACITY;  // f(+B) = 0 - CAPACITY, exact

  float lam_est = 0.0f;  // previous pick, warm start across iters (R15: must
                         // be the pick itself, NOT an extrapolation)

  // g(lam) - CAPACITY over the 4-lane group (16 items/lane, 4 indep chains).
  auto eval_f = [&](float lam) -> float {
    const v2f nl = {-lam, -lam};
    v2f q[4];
#pragma unroll
    for (int p = 0; p < 4; ++p) {
      const v2f z0 = __builtin_elementwise_fma(nl, w[2 * p], y[2 * p]);
      const v2f z1 = __builtin_elementwise_fma(nl, w[2 * p + 1], y[2 * p + 1]);
      const v2f t0 = {clip01(z0.x), clip01(z0.y)};
      const v2f t1 = {clip01(z1.x), clip01(z1.y)};
      const v2f qq = w[2 * p] * t0;
      q[p] = __builtin_elementwise_fma(w[2 * p + 1], t1, qq);
    }
    const v2f qs = (q[0] + q[1]) + (q[2] + q[3]);
    return grp4_sum(qs.x + qs.y) - CAPACITY;
  };

  // ---- multiplier root-find on [-B, +B] + epilogue x = clip(y - lam*w) ----
  // R7/R10-proven solver: warm probe + 2 Illinois false positions + exact
  // final pick (3 evals = verified accuracy floor, R8; no data-dependent
  // freeze, R6; wave-uniform eval3 skip, R10). R16: skip threshold widened
  // 1e-5 -> 1e-4. Per-fire lam perturbation <= 1e-4 -> x perturbation
  // <= 1e-3 (w <= 10), below the bf16 output quantization step and one-shot
  // per solve (each solve re-brackets from exact +-B endpoints). The skip is
  // a 16-row wave conjunction, so firing frequency is highly
  // threshold-sensitive; this buys chain-length where the kernel is
  // latency-bound.
  // Illinois halvings (0.5*flo / 0.5*fhi, selected by prevpos) are computed
  // BEFORE f lands -- off the critical path.
  auto solve_project = [&]() {
    float lo = -B, hi = B, flo = flo0, fhi = fhi0;
    bool prevpos;

    // eval 1: warm probe. lam_est is always inside [-B, B]: it is either 0
    // (first iteration) or a med3 clamp into a sub-bracket of [-B, B], and
    // B is a per-row constant -- so no clamp is needed here.
    float lam = lam_est;
    {
      const float f = eval_f(lam);
      const bool pos = f > 0.0f;
      flo = pos ? f : flo;
      lo  = pos ? lam : lo;
      fhi = pos ? fhi : f;
      hi  = pos ? hi : lam;
      prevpos = pos;
    }

    // eval 2: false position with Illinois halving (halved values selected
    // by prevpos, computed before f arrives)
    {
      lam = __builtin_amdgcn_fmed3f(false_pos(lo, flo, hi, fhi), lo, hi);
      const float fhi_a = prevpos ? 0.5f * fhi : fhi;  // off critical path
      const float flo_a = prevpos ? flo : 0.5f * flo;
      const float f = eval_f(lam);
      const bool pos = f > 0.0f;
      flo = pos ? f : flo_a;
      lo  = pos ? lam : lo;
      fhi = pos ? fhi_a : f;
      hi  = pos ? hi : lam;
      prevpos = pos;
    }

    // eval 3: identical Illinois step, skipped only if the whole wave's
    // brackets have already collapsed below 1e-4 (skip perturbs lam by
    // <= 1e-4, one-shot, non-accumulating; R16 widened from 1e-5).
    const bool tiny = (hi - lo) <= 1e-4f;
    if (!__all(tiny)) {
      lam = __builtin_amdgcn_fmed3f(false_pos(lo, flo, hi, fhi), lo, hi);
      const float fhi_a = prevpos ? 0.5f * fhi : fhi;
      const float flo_a = prevpos ? flo : 0.5f * flo;
      const float f = eval_f(lam);
      const bool pos = f > 0.0f;
      flo = pos ? f : flo_a;
      lo  = pos ? lam : lo;
      fhi = pos ? fhi_a : f;
      hi  = pos ? hi : lam;
    }

    // final derivative-free pick (no extra eval)
    const float pick =
        __builtin_amdgcn_fmed3f(false_pos(lo, flo, hi, fhi), lo, hi);
    lam_est = pick;
    const float lam_use = fmaxf(pick, 0.0f);  // inactive constraint -> 0

    const v2f nl = {-lam_use, -lam_use};
#pragma unroll
    for (int p = 0; p < 8; ++p) {
      const v2f z = __builtin_elementwise_fma(nl, w[p], y[p]);
      x[p] = (v2f){clip01(z.x), clip01(z.y)};
    }
  };

  // Iteration 0 peeled: y is already clip01(c).
  solve_project();

#pragma unroll 2
  for (int it = 1; it <= N_PGD; ++it) {
    // y = x + eta*(c - x/||x||) = (1 - eta/||x||)*x + eta*c
    v2f a = x[0] * x[0];
    a = __builtin_elementwise_fma(x[1], x[1], a);
    v2f b = x[2] * x[2];
    b = __builtin_elementwise_fma(x[3], x[3], b);
    v2f c2 = x[4] * x[4];
    c2 = __builtin_elementwise_fma(x[5], x[5], c2);
    v2f d = x[6] * x[6];
    d = __builtin_elementwise_fma(x[7], x[7], d);
    const v2f ab = (a + b) + (c2 + d);
    const float s2  = grp4_sum(ab.x + ab.y);
    const float inv = __builtin_amdgcn_rsqf(s2 + 1e-12f);
    const float s   = 1.0f - ETA * inv;
    const v2f sv = {s, s};
#pragma unroll
    for (int p = 0; p < 8; ++p)
      y[p] = __builtin_elementwise_fma(sv, x[p], ec[p]);

    solve_project();
  }

#pragma unroll
  for (int u = 0; u < 4; ++u) {
    *reinterpret_cast<float4*>(out + base + 4 * u) =
        make_float4(x[2 * u].x, x[2 * u].y, x[2 * u + 1].x, x[2 * u + 1].y);
  }
}

extern "C" void kernel_launch(void* const* d_in, const int* in_sizes, int n_in,
                              void* d_out, int out_size, void* d_ws, size_t ws_size,
                              hipStream_t stream) {
  const float* costs   = (const float*)d_in[0];
  const float* weights = (const float*)d_in[1];
  float* out           = (float*)d_out;

  const int n_rows  = in_sizes[0] / N_ITEMS;  // 16384
  const int threads = n_rows * 4;             // 4 lanes per row
  dim3 block(256);
  dim3 grid(threads / 256);
  pgd_knapsack<<<grid, block, 0, stream>>>(costs, weights, out);
}

// Round 3
// 112.150 us; speedup vs baseline: 1.0060x; 1.0049x over previous
//
#include <hip/hip_runtime.h>

// Problem constants (match reference)
#define N_ITEMS   64
#define CAPACITY  102.0f
#define N_PGD     120
#define ETA       0.1f

typedef float v2f __attribute__((ext_vector_type(2)));

// ---- DPP helpers: butterfly reductions over 4-lane quads ------------------
//   0xB1 = quad_perm [1,0,3,2] -> lane ^ 1
//   0x4E = quad_perm [2,3,0,1] -> lane ^ 2
// Both are quad-local, so a 4-lane problem-group never leaks into neighbors.
// All 4 lanes end bitwise-identical after the butterfly, so per-group
// decisions (bracket updates, lam) are uniform within the group.
template <int CTRL>
__device__ __forceinline__ float dpp_movf(float x) {
  return __builtin_bit_cast(
      float, __builtin_amdgcn_update_dpp(0, __builtin_bit_cast(int, x), CTRL,
                                         0xF, 0xF, true));
}

__device__ __forceinline__ float grp4_sum(float x) {
  x += dpp_movf<0xB1>(x);
  x += dpp_movf<0x4E>(x);
  return x;
}

__device__ __forceinline__ float grp4_max(float x) {
  x = fmaxf(x, dpp_movf<0xB1>(x));
  x = fmaxf(x, dpp_movf<0x4E>(x));
  return x;
}

__device__ __forceinline__ float clip01(float z) {
  return __builtin_amdgcn_fmed3f(z, 0.0f, 1.0f);  // single v_med3_f32
}

// Bracket false-position (R0-proven final pick). Invariant: flo > 0 >= fhi
// (Illinois halving preserves signs), so fhi - flo < 0 strictly; the med3
// clamp at the call site absorbs rounding excursions outside [lo, hi].
__device__ __forceinline__ float false_pos(float lo, float flo, float hi,
                                           float fhi) {
  const float t = fhi * __builtin_amdgcn_rcpf(fhi - flo);
  return fmaf(-t, hi - lo, hi);  // hi - fhi*(hi-lo)/(fhi-flo)
}

// 4 lanes per row, 16 items per lane. 16384 rows -> 65536 threads
// (1024 waves = 1 wave/SIMD). Measured optimum (R13) across the explored
// config space: 8-lane/2-waves and dual-row layouts cost more instructions
// than their utilization recovery (R7/R11); speculation/probe-pairing on the
// root-finder chain is net-neutral or worse (R12/R14); root extrapolation
// across PGD iterations breaks limit-cycle rows (R15 -- FAILED accuracy,
// reverted); bracket-width skip-threshold widening is NULL because the
// post-eval2 bracket width is bimodal -- tiny when eval2 crosses the root,
// ~B when it doesn't (R16).
__global__ __launch_bounds__(256, 1) void pgd_knapsack(
    const float* __restrict__ costs, const float* __restrict__ weights,
    float* __restrict__ out) {
  const int tid  = blockIdx.x * 256 + threadIdx.x;
  const int sub  = tid & 3;                 // lane within row-group
  const int base = (tid >> 2) * N_ITEMS + sub * 16;

  v2f w[8], ec[8], x[8], y[8];

  float B;     // bracket half-width: g(-B) = sum(w), g(+B) = 0 by construction
  float flo0;  // f(-B) = sum(w) - CAPACITY, exact, no eval needed
  {
    float cab = 0.0f;
#pragma unroll
    for (int u = 0; u < 4; ++u) {
      const float4 cq = *reinterpret_cast<const float4*>(costs + base + 4 * u);
      const float4 wq =
          *reinterpret_cast<const float4*>(weights + sub * 16 + 4 * u);
      w[2 * u]      = (v2f){wq.x, wq.y};
      w[2 * u + 1]  = (v2f){wq.z, wq.w};
      ec[2 * u]     = (v2f){ETA * cq.x, ETA * cq.y};
      ec[2 * u + 1] = (v2f){ETA * cq.z, ETA * cq.w};
      y[2 * u]      = (v2f){clip01(cq.x), clip01(cq.y)};
      y[2 * u + 1]  = (v2f){clip01(cq.z), clip01(cq.w)};
      cab = fmaxf(cab, fmaxf(fmaxf(fabsf(cq.x), fabsf(cq.y)),
                             fmaxf(fabsf(cq.z), fabsf(cq.w))));
    }
    cab = grp4_max(cab);
    // Every PGD iterate satisfies y_j in [-0.1 - eta*cab, 1 + eta*cab]
    // (since (1 - eta/||x||) * x_j in [-eta, 1]); with w_j >= 1 this makes
    // +-B a valid bracket: all coords clipped to 1 at -B, to 0 at +B.
    B = fmaf(ETA, cab, 1.1f) + 1e-3f;
    v2f sw = (w[0] + w[1]) + (w[2] + w[3]);
    sw = sw + ((w[4] + w[5]) + (w[6] + w[7]));
    flo0 = grp4_sum(sw.x + sw.y) - CAPACITY;  // = 340 - 102, exact
  }
  const float fhi0 = -CAPACITY;  // f(+B) = 0 - CAPACITY, exact

  float lam_est = 0.0f;  // previous pick, warm start across iters (R15: must
                         // be the pick itself, NOT an extrapolation)
  // R17: carried inverse secant slope 1/f' (negative; f monotone
  // decreasing). The active set -- hence the root's piece slope
  // sum_S w_j^2 -- freezes after the early trajectory, so a Newton step
  // from the warm start lands exactly on the root's linear piece and
  // |f(eval2)| collapses to float rounding. Init: order-of-magnitude guess
  // (slope ~ 400); any error is absorbed by the bracket clamp + eval3.
  float inv_sl = -0.0025f;

  // g(lam) - CAPACITY over the 4-lane group (16 items/lane, 4 indep chains).
  auto eval_f = [&](float lam) -> float {
    const v2f nl = {-lam, -lam};
    v2f q[4];
#pragma unroll
    for (int p = 0; p < 4; ++p) {
      const v2f z0 = __builtin_elementwise_fma(nl, w[2 * p], y[2 * p]);
      const v2f z1 = __builtin_elementwise_fma(nl, w[2 * p + 1], y[2 * p + 1]);
      const v2f t0 = {clip01(z0.x), clip01(z0.y)};
      const v2f t1 = {clip01(z1.x), clip01(z1.y)};
      const v2f qq = w[2 * p] * t0;
      q[p] = __builtin_elementwise_fma(w[2 * p + 1], t1, qq);
    }
    const v2f qs = (q[0] + q[1]) + (q[2] + q[3]);
    return grp4_sum(qs.x + qs.y) - CAPACITY;
  };

  // Guarded secant inverse-slope update from two evaluated points.
  // Monotone-decreasing f => legitimate secant slope < 0. Degenerate cases
  // (df == 0, dl == 0, NaN from 0*inf) all fail the (df!=0 && cand<0) test
  // and keep the previous value. Magnitude cap at 1: any interval
  // containing an interior coord has slope >= min w^2 = 1; flat-piece
  // secants (slope < 1) would overshoot wildly and waste the clamp.
  // (fmaxf(NaN, -1) = -1, then df!=0 decides -- safe.)
  auto upd_inv = [&](float la, float fa, float lb, float fb) {
    const float df = fb - fa;
    float cand = (lb - la) * __builtin_amdgcn_rcpf(df);
    cand = fmaxf(cand, -1.0f);
    const bool ok = (df != 0.0f) & (cand < 0.0f);
    inv_sl = ok ? cand : inv_sl;
  };

  // ---- multiplier root-find on [-B, +B] + epilogue x = clip(y - lam*w) ----
  // R17 solver: warm probe + Newton-placed eval2/eval3 (carried secant
  // inverse slope, bracket-clamped) + R0-proven bracket/Illinois updates.
  // Skip eval3 when __all(|f2| <= 3e-4 or width <= 1e-4): accepting lam with
  // |f(lam)| <= ftol gives per-coord x error <= ftol/w_j (f and x both
  // monotone in lam => sum w_j |dx_j| = |df|), one-shot per solve. Non-skip
  // final pick stays the R0 bracket false position; skip pick is lam2
  // itself (the rigorously bounded point -- R15 lesson: no unverifiable
  // extrapolations).
  auto solve_project = [&]() {
    float lo = -B, hi = B, flo = flo0, fhi = fhi0;

    // eval 1: warm probe. lam_est is always inside [-B, B]: it is either 0
    // (first iteration) or a med3 clamp into a sub-bracket of [-B, B], and
    // B is a per-row constant -- so no clamp is needed here.
    const float l1 = lam_est;
    const float f1 = eval_f(l1);
    const bool pos1 = f1 > 0.0f;
    flo = pos1 ? f1 : flo;
    lo  = pos1 ? l1 : lo;
    fhi = pos1 ? fhi : f1;
    hi  = pos1 ? hi : l1;

    // eval 2: Newton step from the carried inverse slope, bracket-clamped.
    // (2 ops on the critical path vs false_pos's rcp chain.)
    const float l2 = __builtin_amdgcn_fmed3f(fmaf(-f1, inv_sl, l1), lo, hi);
    const float fhi_a = pos1 ? 0.5f * fhi : fhi;  // Illinois, off crit path
    const float flo_a = pos1 ? flo : 0.5f * flo;
    const float f2 = eval_f(l2);
    const bool pos2 = f2 > 0.0f;
    flo = pos2 ? f2 : flo_a;
    lo  = pos2 ? l2 : lo;
    fhi = pos2 ? fhi_a : f2;
    hi  = pos2 ? hi : l2;

    upd_inv(l1, f1, l2, f2);

    float pick;
    const bool tiny = (fabsf(f2) <= 3e-4f) | ((hi - lo) <= 1e-4f);
    if (!__all(tiny)) {
      // eval 3: Newton from the refreshed secant, bracket-clamped.
      const float l3 =
          __builtin_amdgcn_fmed3f(fmaf(-f2, inv_sl, l2), lo, hi);
      const float fhi_b = pos2 ? 0.5f * fhi : fhi;
      const float flo_b = pos2 ? flo : 0.5f * flo;
      const float f3 = eval_f(l3);
      const bool pos3 = f3 > 0.0f;
      flo = pos3 ? f3 : flo_b;
      lo  = pos3 ? l3 : lo;
      fhi = pos3 ? fhi_b : f3;
      hi  = pos3 ? hi : l3;
      upd_inv(l2, f2, l3, f3);
      // final derivative-free pick (no extra eval) -- R0-proven form
      pick = __builtin_amdgcn_fmed3f(false_pos(lo, flo, hi, fhi), lo, hi);
    } else {
      // |f(l2)| <= ftol certified: x error <= ftol elementwise.
      pick = l2;
    }

    lam_est = pick;
    const float lam_use = fmaxf(pick, 0.0f);  // inactive constraint -> 0

    const v2f nl = {-lam_use, -lam_use};
#pragma unroll
    for (int p = 0; p < 8; ++p) {
      const v2f z = __builtin_elementwise_fma(nl, w[p], y[p]);
      x[p] = (v2f){clip01(z.x), clip01(z.y)};
    }
  };

  // Iteration 0 peeled: y is already clip01(c).
  solve_project();

#pragma unroll 2
  for (int it = 1; it <= N_PGD; ++it) {
    // y = x + eta*(c - x/||x||) = (1 - eta/||x||)*x + eta*c
    v2f a = x[0] * x[0];
    a = __builtin_elementwise_fma(x[1], x[1], a);
    v2f b = x[2] * x[2];
    b = __builtin_elementwise_fma(x[3], x[3], b);
    v2f c2 = x[4] * x[4];
    c2 = __builtin_elementwise_fma(x[5], x[5], c2);
    v2f d = x[6] * x[6];
    d = __builtin_elementwise_fma(x[7], x[7], d);
    const v2f ab = (a + b) + (c2 + d);
    const float s2  = grp4_sum(ab.x + ab.y);
    const float inv = __builtin_amdgcn_rsqf(s2 + 1e-12f);
    const float s   = 1.0f - ETA * inv;
    const v2f sv = {s, s};
#pragma unroll
    for (int p = 0; p < 8; ++p)
      y[p] = __builtin_elementwise_fma(sv, x[p], ec[p]);

    solve_project();
  }

#pragma unroll
  for (int u = 0; u < 4; ++u) {
    *reinterpret_cast<float4*>(out + base + 4 * u) =
        make_float4(x[2 * u].x, x[2 * u].y, x[2 * u + 1].x, x[2 * u + 1].y);
  }
}

extern "C" void kernel_launch(void* const* d_in, const int* in_sizes, int n_in,
                              void* d_out, int out_size, void* d_ws, size_t ws_size,
                              hipStream_t stream) {
  const float* costs   = (const float*)d_in[0];
  const float* weights = (const float*)d_in[1];
  float* out           = (float*)d_out;

  const int n_rows  = in_sizes[0] / N_ITEMS;  // 16384
  const int threads = n_rows * 4;             // 4 lanes per row
  dim3 block(256);
  dim3 grid(threads / 256);
  pgd_knapsack<<<grid, block, 0, stream>>>(costs, weights, out);
}

// Round 4
// 107.494 us; speedup vs baseline: 1.0496x; 1.0433x over previous
//
#include <hip/hip_runtime.h>

// Problem constants (match reference)
#define N_ITEMS   64
#define CAPACITY  102.0f
#define N_PGD     120
#define ETA       0.1f

// R18: certified-|f| skip gate. Accepting lam with |f(lam)| <= FTOL gives
// sum_j w_j |dx_j| = |df| <= FTOL, i.e. elementwise x-error <= FTOL (w>=1)
// -- below the bf16 output quantization step (3.9e-3). FTOL is only the
// GATE: the injected error is the actual |f2| (~1e-4 eval noise in steady
// state); large-|f2| transients fail the gate and still run eval3.
#define FTOL 1e-3f

typedef float v2f __attribute__((ext_vector_type(2)));

// ---- DPP helpers: butterfly reductions over 4-lane quads ------------------
//   0xB1 = quad_perm [1,0,3,2] -> lane ^ 1
//   0x4E = quad_perm [2,3,0,1] -> lane ^ 2
// Both are quad-local, so a 4-lane problem-group never leaks into neighbors.
// All 4 lanes end bitwise-identical after the butterfly, so per-group
// decisions (bracket updates, lam) are uniform within the group.
template <int CTRL>
__device__ __forceinline__ float dpp_movf(float x) {
  return __builtin_bit_cast(
      float, __builtin_amdgcn_update_dpp(0, __builtin_bit_cast(int, x), CTRL,
                                         0xF, 0xF, true));
}

__device__ __forceinline__ float grp4_sum(float x) {
  x += dpp_movf<0xB1>(x);
  x += dpp_movf<0x4E>(x);
  return x;
}

__device__ __forceinline__ float grp4_max(float x) {
  x = fmaxf(x, dpp_movf<0xB1>(x));
  x = fmaxf(x, dpp_movf<0x4E>(x));
  return x;
}

__device__ __forceinline__ float clip01(float z) {
  return __builtin_amdgcn_fmed3f(z, 0.0f, 1.0f);  // single v_med3_f32
}

// 4 lanes per row, 16 items per lane. 16384 rows -> 65536 threads
// (1024 waves = 1 wave/SIMD). Measured optimum (R13) across the explored
// config space: 8-lane/2-waves and dual-row layouts cost more instructions
// than their utilization recovery (R7/R11); speculation/probe-pairing on the
// root-finder chain is net-neutral or worse (R12/R14); root extrapolation
// across PGD iterations breaks limit-cycle rows (R15 -- FAILED accuracy,
// reverted); bracket-width skip-threshold widening is NULL because the
// post-eval2 bracket width is bimodal (R16); |f|-gate at 3e-4 is NULL
// because it sits at eval_f's own ~1e-4 rounding-noise floor and the
// 16-row wave conjunction crushes per-row fire probabilities (R17).
__global__ __launch_bounds__(256, 1) void pgd_knapsack(
    const float* __restrict__ costs, const float* __restrict__ weights,
    float* __restrict__ out) {
  const int tid  = blockIdx.x * 256 + threadIdx.x;
  const int sub  = tid & 3;                 // lane within row-group
  const int base = (tid >> 2) * N_ITEMS + sub * 16;

  v2f w[8], ec[8], x[8], y[8];

  float B;     // bracket half-width: g(-B) = sum(w), g(+B) = 0 by construction
  float flo0;  // f(-B) = sum(w) - CAPACITY, exact, no eval needed
  {
    float cab = 0.0f;
#pragma unroll
    for (int u = 0; u < 4; ++u) {
      const float4 cq = *reinterpret_cast<const float4*>(costs + base + 4 * u);
      const float4 wq =
          *reinterpret_cast<const float4*>(weights + sub * 16 + 4 * u);
      w[2 * u]      = (v2f){wq.x, wq.y};
      w[2 * u + 1]  = (v2f){wq.z, wq.w};
      ec[2 * u]     = (v2f){ETA * cq.x, ETA * cq.y};
      ec[2 * u + 1] = (v2f){ETA * cq.z, ETA * cq.w};
      y[2 * u]      = (v2f){clip01(cq.x), clip01(cq.y)};
      y[2 * u + 1]  = (v2f){clip01(cq.z), clip01(cq.w)};
      cab = fmaxf(cab, fmaxf(fmaxf(fabsf(cq.x), fabsf(cq.y)),
                             fmaxf(fabsf(cq.z), fabsf(cq.w))));
    }
    cab = grp4_max(cab);
    // Every PGD iterate satisfies y_j in [-0.1 - eta*cab, 1 + eta*cab]
    // (since (1 - eta/||x||) * x_j in [-eta, 1]); with w_j >= 1 this makes
    // +-B a valid bracket: all coords clipped to 1 at -B, to 0 at +B.
    B = fmaf(ETA, cab, 1.1f) + 1e-3f;
    v2f sw = (w[0] + w[1]) + (w[2] + w[3]);
    sw = sw + ((w[4] + w[5]) + (w[6] + w[7]));
    flo0 = grp4_sum(sw.x + sw.y) - CAPACITY;  // = 340 - 102, exact
  }
  const float fhi0 = -CAPACITY;  // f(+B) = 0 - CAPACITY, exact

  float lam_est = 0.0f;  // previous pick, warm start across iters (R15: must
                         // be the pick itself, NOT an extrapolation)
  // Carried inverse secant slope 1/f' (negative; f monotone decreasing).
  // The active set -- hence the root's piece slope sum_S w_j^2 -- freezes
  // after the early trajectory, so a Newton step from the warm start lands
  // on the root's linear piece. Init: order-of-magnitude guess (slope ~400).
  float inv_sl = -0.0025f;

  // g(lam) - CAPACITY over the 4-lane group (16 items/lane, 4 indep chains).
  auto eval_f = [&](float lam) -> float {
    const v2f nl = {-lam, -lam};
    v2f q[4];
#pragma unroll
    for (int p = 0; p < 4; ++p) {
      const v2f z0 = __builtin_elementwise_fma(nl, w[2 * p], y[2 * p]);
      const v2f z1 = __builtin_elementwise_fma(nl, w[2 * p + 1], y[2 * p + 1]);
      const v2f t0 = {clip01(z0.x), clip01(z0.y)};
      const v2f t1 = {clip01(z1.x), clip01(z1.y)};
      const v2f qq = w[2 * p] * t0;
      q[p] = __builtin_elementwise_fma(w[2 * p + 1], t1, qq);
    }
    const v2f qs = (q[0] + q[1]) + (q[2] + q[3]);
    return grp4_sum(qs.x + qs.y) - CAPACITY;
  };

  // Guarded secant inverse-slope from two evaluated points, fallback fb.
  // Monotone-decreasing f => legitimate secant slope < 0. |df| > 1e-3 guard:
  // converged point pairs are rounding-noise-dominated (df ~ 1e-4) and would
  // poison the carried slope (e.g. apparent slope -10 from noise). Cap at -1:
  // any interval containing an interior coord has slope >= min w^2 = 1;
  // flat-piece secants would overshoot wildly. (fmaxf(NaN,-1) = -1, then the
  // df-guard decides -- safe.)
  auto secant_inv = [](float la, float fa, float lb, float fb_, float fb) {
    const float df = fb_ - fa;
    float cand = (lb - la) * __builtin_amdgcn_rcpf(df);
    cand = fmaxf(cand, -1.0f);
    const bool ok = (fabsf(df) > 1e-3f) & (cand < 0.0f);
    return ok ? cand : fb;
  };

  // ---- multiplier root-find on [-B, +B] + epilogue x = clip(y - lam*w) ----
  // R18 solver: warm probe + Newton-placed eval2/eval3 (carried secant
  // inverse slope, bracket-clamped) + R0-proven bracket/Illinois updates +
  // Newton final pick (refreshed slope, fmaf+med3 -- no rcp on the chain).
  // eval3 placement uses the CARRIED slope so the (l1,f1,l2,f2) secant rcp
  // runs in eval3's shadow, feeding only the final pick and the next solve.
  // Skip eval3 when __all(|f2| <= FTOL or width <= 1e-4); skip pick is l2
  // itself, the rigorously-certified point (R15 lesson: no unverifiable
  // extrapolations as picks).
  auto solve_project = [&]() {
    float lo = -B, hi = B, flo = flo0, fhi = fhi0;

    // eval 1: warm probe. lam_est is always inside [-B, B]: it is either 0
    // (first iteration) or a med3 clamp into a sub-bracket of [-B, B], and
    // B is a per-row constant -- so no clamp is needed here.
    const float l1 = lam_est;
    const float f1 = eval_f(l1);
    const bool pos1 = f1 > 0.0f;
    flo = pos1 ? f1 : flo;
    lo  = pos1 ? l1 : lo;
    fhi = pos1 ? fhi : f1;
    hi  = pos1 ? hi : l1;

    // eval 2: Newton step from the carried inverse slope, bracket-clamped.
    const float l2 = __builtin_amdgcn_fmed3f(fmaf(-f1, inv_sl, l1), lo, hi);
    const float fhi_a = pos1 ? 0.5f * fhi : fhi;  // Illinois, off crit path
    const float flo_a = pos1 ? flo : 0.5f * flo;
    const float f2 = eval_f(l2);
    const bool pos2 = f2 > 0.0f;
    flo = pos2 ? f2 : flo_a;
    lo  = pos2 ? l2 : lo;
    fhi = pos2 ? fhi_a : f2;
    hi  = pos2 ? hi : l2;

    // Refreshed slope A from (l1,f1)-(l2,f2). Dataflow: NOT on the f2->l3
    // chain (l3 uses the carried inv_sl); the rcp overlaps eval3.
    const float A = secant_inv(l1, f1, l2, f2, inv_sl);

    float pick;
    const bool tiny = (fabsf(f2) <= FTOL) | ((hi - lo) <= 1e-4f);
    if (!__all(tiny)) {
      // eval 3: Newton placement with the CARRIED slope (2 ops after f2).
      const float l3 =
          __builtin_amdgcn_fmed3f(fmaf(-f2, inv_sl, l2), lo, hi);
      const float fhi_b = pos2 ? 0.5f * fhi : fhi;
      const float flo_b = pos2 ? flo : 0.5f * flo;
      const float f3 = eval_f(l3);
      const bool pos3 = f3 > 0.0f;
      flo = pos3 ? f3 : flo_b;
      lo  = pos3 ? l3 : lo;
      fhi = pos3 ? fhi_b : f3;
      hi  = pos3 ? hi : l3;
      // Final pick: Newton from (l3,f3) with refreshed slope A -- fmaf+med3,
      // no rcp on the critical path. Exact on the root's linear piece;
      // bracket-clamped otherwise (same accuracy class as false position).
      pick = __builtin_amdgcn_fmed3f(fmaf(-f3, A, l3), lo, hi);
      // Slope for the next solve: freshest pair, fallback A.
      inv_sl = secant_inv(l2, f2, l3, f3, A);
    } else {
      // |f(l2)| <= FTOL certified: x error <= FTOL elementwise.
      pick = l2;
      inv_sl = A;
    }

    lam_est = pick;
    const float lam_use = fmaxf(pick, 0.0f);  // inactive constraint -> 0

    const v2f nl = {-lam_use, -lam_use};
#pragma unroll
    for (int p = 0; p < 8; ++p) {
      const v2f z = __builtin_elementwise_fma(nl, w[p], y[p]);
      x[p] = (v2f){clip01(z.x), clip01(z.y)};
    }
  };

  // Iteration 0 peeled: y is already clip01(c).
  solve_project();

#pragma unroll 2
  for (int it = 1; it <= N_PGD; ++it) {
    // y = x + eta*(c - x/||x||) = (1 - eta/||x||)*x + eta*c
    v2f a = x[0] * x[0];
    a = __builtin_elementwise_fma(x[1], x[1], a);
    v2f b = x[2] * x[2];
    b = __builtin_elementwise_fma(x[3], x[3], b);
    v2f c2 = x[4] * x[4];
    c2 = __builtin_elementwise_fma(x[5], x[5], c2);
    v2f d = x[6] * x[6];
    d = __builtin_elementwise_fma(x[7], x[7], d);
    const v2f ab = (a + b) + (c2 + d);
    const float s2  = grp4_sum(ab.x + ab.y);
    const float inv = __builtin_amdgcn_rsqf(s2 + 1e-12f);
    const float s   = 1.0f - ETA * inv;
    const v2f sv = {s, s};
#pragma unroll
    for (int p = 0; p < 8; ++p)
      y[p] = __builtin_elementwise_fma(sv, x[p], ec[p]);

    solve_project();
  }

#pragma unroll
  for (int u = 0; u < 4; ++u) {
    *reinterpret_cast<float4*>(out + base + 4 * u) =
        make_float4(x[2 * u].x, x[2 * u].y, x[2 * u + 1].x, x[2 * u + 1].y);
  }
}

extern "C" void kernel_launch(void* const* d_in, const int* in_sizes, int n_in,
                              void* d_out, int out_size, void* d_ws, size_t ws_size,
                              hipStream_t stream) {
  const float* costs   = (const float*)d_in[0];
  const float* weights = (const float*)d_in[1];
  float* out           = (float*)d_out;

  const int n_rows  = in_sizes[0] / N_ITEMS;  // 16384
  const int threads = n_rows * 4;             // 4 lanes per row
  dim3 block(256);
  dim3 grid(threads / 256);
  pgd_knapsack<<<grid, block, 0, stream>>>(costs, weights, out);
}